// Round 3
// baseline (910.990 us; speedup 1.0000x reference)
//
#include <hip/hip_runtime.h>
#include <hip/hip_bf16.h>
#include <stdint.h>

#define SDIM 2048
#define DDIM 128
#define NKT  64   // 2048 / 32 k-tiles

typedef __bf16 bf16x8 __attribute__((ext_vector_type(8)));
typedef float  f32x16 __attribute__((ext_vector_type(16)));

// mask (1,1,S,S) int32 -> transposed bitmask bitsT[kt][row], bit j of word = mask[row][kt*32+j]
__global__ void build_bits_kernel(const int* __restrict__ mask, uint32_t* __restrict__ bitsT) {
  const int id   = blockIdx.x * 4 + (threadIdx.x >> 6);
  const int lane = threadIdx.x & 63;
  const int row  = id >> 5;   // 0..2047
  const int kc   = id & 31;   // 64-wide chunk
  const int m = mask[(size_t)row * SDIM + kc * 64 + lane];
  const unsigned long long b = __ballot(m != 0);
  if (lane == 0)  bitsT[(size_t)(kc * 2    ) * SDIM + row] = (uint32_t)(b & 0xffffffffull);
  if (lane == 32) bitsT[(size_t)(kc * 2 + 1) * SDIM + row] = (uint32_t)(b >> 32);
}

__launch_bounds__(256, 2)
__global__ void attn_kernel(const float* __restrict__ qg, const float* __restrict__ kg,
                            const float* __restrict__ vg, const uint32_t* __restrict__ bitsT,
                            float* __restrict__ outg, float* __restrict__ attng) {
  // LDS: K tile (bf16, chunk-swizzled), V^T tile, per-wave P tile, mask words
  __shared__ __align__(16) __bf16 KR[32 * 128];
  __shared__ __align__(16) __bf16 VTR[128 * 32];
  __shared__ __align__(16) __bf16 PR[4][32 * 32];
  __shared__ uint32_t MW[128];

  const int bid  = blockIdx.x;
  const int swzb = (bid & 7) * 64 + (bid >> 3);   // XCD-contiguous: 64 blocks (4 heads) per XCD
  const int head = swzb >> 4;   // 0..31  (b*16+h)
  const int qb   = swzb & 15;   // 0..15  (128 q-rows each)
  const int tid  = threadIdx.x;
  const int wv   = tid >> 6;
  const int lane = tid & 63;
  const int col  = lane & 31;
  const int hi   = lane >> 5;

  const float* qh = qg + (size_t)head * SDIM * DDIM;
  const float* kh = kg + (size_t)head * SDIM * DDIM;
  const float* vh = vg + (size_t)head * SDIM * DDIM;
  float* outh  = outg  + (size_t)head * SDIM * DDIM;
  float* attnh = attng + (size_t)head * SDIM * SDIM;

  const int qrow0 = qb * 128 + wv * 32;           // this wave's 32 q-rows
  const float cscale = 1.4426950408889634f * 0.08838834764831845f; // log2(e)/sqrt(128)
  const uint32_t lanebit = 1u << col;

  // staging mapping: row = tid&31, 16 d per thread
  const int str = tid & 31;
  const int sdb = (tid >> 5) * 16;

  // C/D layout rows for 32x32 mfma (verified): row = (r&3)+8*(r>>2)+4*hi
  int rowl[16];
#pragma unroll
  for (int r = 0; r < 16; ++r) rowl[r] = wv * 32 + (r & 3) + 8 * (r >> 2) + 4 * hi;

  auto stage_k = [&](int kt) {
    const float* src = kh + (size_t)(kt * 32 + str) * DDIM + sdb;
    float4 a0 = *(const float4*)(src + 0);
    float4 a1 = *(const float4*)(src + 4);
    float4 a2 = *(const float4*)(src + 8);
    float4 a3 = *(const float4*)(src + 12);
    bf16x8 w0, w1;
    w0[0]=(__bf16)a0.x; w0[1]=(__bf16)a0.y; w0[2]=(__bf16)a0.z; w0[3]=(__bf16)a0.w;
    w0[4]=(__bf16)a1.x; w0[5]=(__bf16)a1.y; w0[6]=(__bf16)a1.z; w0[7]=(__bf16)a1.w;
    w1[0]=(__bf16)a2.x; w1[1]=(__bf16)a2.y; w1[2]=(__bf16)a2.z; w1[3]=(__bf16)a2.w;
    w1[4]=(__bf16)a3.x; w1[5]=(__bf16)a3.y; w1[6]=(__bf16)a3.z; w1[7]=(__bf16)a3.w;
    const int c0 = sdb >> 3;
    *(bf16x8*)&KR[str * 128 + (((c0    ) ^ (str & 15))) * 8] = w0;
    *(bf16x8*)&KR[str * 128 + (((c0 + 1) ^ (str & 15))) * 8] = w1;
  };
  auto stage_vt = [&](int kt) {   // transpose V tile into LDS: VTR[d][k-local]
    const float* src = vh + (size_t)(kt * 32 + str) * DDIM + sdb;
    float4 a0 = *(const float4*)(src + 0);
    float4 a1 = *(const float4*)(src + 4);
    float4 a2 = *(const float4*)(src + 8);
    float4 a3 = *(const float4*)(src + 12);
    float vv[16] = {a0.x,a0.y,a0.z,a0.w, a1.x,a1.y,a1.z,a1.w,
                    a2.x,a2.y,a2.z,a2.w, a3.x,a3.y,a3.z,a3.w};
#pragma unroll
    for (int j = 0; j < 16; ++j) {
      const int d = sdb + j;
      VTR[d * 32 + (((str >> 3) ^ ((d >> 1) & 3)) << 3) + (str & 7)] = (__bf16)vv[j];
    }
  };
  auto stage_mw = [&](int kt) {
    if (tid < 128) MW[tid] = bitsT[(size_t)kt * SDIM + qb * 128 + tid];
  };

  // ---- Q fragments, held in registers for the whole kernel ----
  bf16x8 qf[8];
#pragma unroll
  for (int s = 0; s < 8; ++s) {
    const float* src = qh + (size_t)(qrow0 + col) * DDIM + s * 16 + hi * 8;
    float4 f0 = *(const float4*)(src);
    float4 f1 = *(const float4*)(src + 4);
    bf16x8 t;
    t[0]=(__bf16)f0.x; t[1]=(__bf16)f0.y; t[2]=(__bf16)f0.z; t[3]=(__bf16)f0.w;
    t[4]=(__bf16)f1.x; t[5]=(__bf16)f1.y; t[6]=(__bf16)f1.z; t[7]=(__bf16)f1.w;
    qf[s] = t;
  }

  float lsum[16];
#pragma unroll
  for (int r = 0; r < 16; ++r) lsum[r] = 0.0f;

  // ================= pass A: softmax denominators =================
  for (int kt = 0; kt < NKT; ++kt) {
    stage_k(kt);
    stage_mw(kt);
    __syncthreads();

    f32x16 sacc = {};
#pragma unroll
    for (int s = 0; s < 8; ++s) {
      bf16x8 kf = *(const bf16x8*)&KR[col * 128 + (((s * 2 + hi) ^ (col & 15))) * 8];
      sacc = __builtin_amdgcn_mfma_f32_32x32x16_bf16(qf[s], kf, sacc, 0, 0, 0);
    }
#pragma unroll
    for (int r = 0; r < 16; ++r) {
      const uint32_t w = MW[rowl[r]];
      float pe = __builtin_amdgcn_exp2f(sacc[r] * cscale);
      pe = (w & lanebit) ? pe : 0.0f;
      lsum[r] += pe;
    }
    __syncthreads();
  }

  // cross-lane row-sum reduction (cols live on lanes 0..31 within each half)
  float loglr[16];
#pragma unroll
  for (int r = 0; r < 16; ++r) {
    float t = lsum[r];
    t += __shfl_xor(t, 1);
    t += __shfl_xor(t, 2);
    t += __shfl_xor(t, 4);
    t += __shfl_xor(t, 8);
    t += __shfl_xor(t, 16);
    loglr[r] = __builtin_amdgcn_logf(fmaxf(t, 1e-30f));  // log2
  }

  f32x16 oacc[4] = {};

  // ================= pass B: write attn + accumulate PV =================
  for (int kt = 0; kt < NKT; ++kt) {
    stage_k(kt);
    stage_vt(kt);
    stage_mw(kt);
    __syncthreads();

    f32x16 sacc = {};
#pragma unroll
    for (int s = 0; s < 8; ++s) {
      bf16x8 kf = *(const bf16x8*)&KR[col * 128 + (((s * 2 + hi) ^ (col & 15))) * 8];
      sacc = __builtin_amdgcn_mfma_f32_32x32x16_bf16(qf[s], kf, sacc, 0, 0, 0);
    }

#pragma unroll
    for (int r = 0; r < 16; ++r) {
      const uint32_t w = MW[rowl[r]];
      float pn = __builtin_amdgcn_exp2f(fmaf(sacc[r], cscale, -loglr[r]));
      pn = (w & lanebit) ? pn : 0.0f;
      __builtin_nontemporal_store(pn,
          &attnh[(size_t)(qb * 128 + rowl[r]) * SDIM + kt * 32 + col]);
      const int qr = rowl[r] - wv * 32;
      PR[wv][qr * 32 + (((col >> 3) ^ ((qr >> 1) & 3)) << 3) + (col & 7)] = (__bf16)pn;
    }

    // PV: out[32q x 128d] += P[32q x 32k] * V[32k x 128d]
#pragma unroll
    for (int ks = 0; ks < 2; ++ks) {
      bf16x8 pf = *(const bf16x8*)&PR[wv][col * 32 + (((ks * 2 + hi) ^ ((col >> 1) & 3)) << 3)];
#pragma unroll
      for (int dt = 0; dt < 4; ++dt) {
        const int d = dt * 32 + col;
        bf16x8 vf = *(const bf16x8*)&VTR[d * 32 + (((ks * 2 + hi) ^ ((d >> 1) & 3)) << 3)];
        oacc[dt] = __builtin_amdgcn_mfma_f32_32x32x16_bf16(pf, vf, oacc[dt], 0, 0, 0);
      }
    }
    __syncthreads();
  }

  // ---- store out ----
#pragma unroll
  for (int dt = 0; dt < 4; ++dt) {
#pragma unroll
    for (int r = 0; r < 16; ++r) {
      __builtin_nontemporal_store(oacc[dt][r],
          &outh[(size_t)(qb * 128 + rowl[r]) * DDIM + dt * 32 + col]);
    }
  }
}

extern "C" void kernel_launch(void* const* d_in, const int* in_sizes, int n_in,
                              void* d_out, int out_size, void* d_ws, size_t ws_size,
                              hipStream_t stream) {
  const float* q   = (const float*)d_in[0];
  const float* k   = (const float*)d_in[1];
  const float* v   = (const float*)d_in[2];
  const int*  mask = (const int*)d_in[3];
  float* outp  = (float*)d_out;
  float* attnp = outp + (size_t)2 * 16 * 2048 * 128;   // out first, then attn
  uint32_t* bitsT = (uint32_t*)d_ws;                   // 64*2048*4 = 512 KB

  hipLaunchKernelGGL(build_bits_kernel, dim3(2048 * 32 / 4), dim3(256), 0, stream, mask, bitsT);
  hipLaunchKernelGGL(attn_kernel, dim3(512), dim3(256), 0, stream,
                     q, k, v, bitsT, outp, attnp);
}